// Round 4
// baseline (1920.544 us; speedup 1.0000x reference)
//
#include <hip/hip_runtime.h>
#include <hip/hip_fp16.h>

namespace {
constexpr int S  = 4096;
constexpr int D  = 64;
constexpr int NH = 16;
constexpr int SW = S / 64;   // 64 mask words (u64) per row
constexpr float kScaleLog2e = 0.125f * 1.44269504088896340736f; // 1/sqrt(64) * log2(e)

typedef _Float16 f16x8 __attribute__((ext_vector_type(8)));
typedef float    f32x4 __attribute__((ext_vector_type(4)));

__device__ inline f32x4 mfma16(f16x8 a, f16x8 b, f32x4 c) {
  return __builtin_amdgcn_mfma_f32_16x16x32_f16(a, b, c, 0, 0, 0);
}

__device__ inline void cvt_store(_Float16* dst, const float4 f) {
  union { ushort4 u; _Float16 h4[4]; } cv;
  cv.h4[0] = (_Float16)f.x; cv.h4[1] = (_Float16)f.y;
  cv.h4[2] = (_Float16)f.z; cv.h4[3] = (_Float16)f.w;
  *(ushort4*)dst = cv.u;
}
} // namespace

// ---- pack bool-as-int mask (S x S) into u64 bitmask: bit=1 means masked out ----
__global__ void pack_mask(const int* __restrict__ mask, unsigned long long* __restrict__ bits) {
  const int lane = threadIdx.x & 63;
  const int wid  = (int)((blockIdx.x * blockDim.x + threadIdx.x) >> 6);
  const int nwv  = (int)((gridDim.x * blockDim.x) >> 6);
  for (int w = wid; w < S * S / 64; w += nwv) {
    const int mv = mask[(size_t)w * 64 + lane];
    const unsigned long long b = __ballot(mv != 0);
    if (lane == 0) bits[w] = b;
  }
}

// ---- streaming rescale: attn[h][row][:] *= rinv[h*S+row]. 2 GB at HBM BW (~350us). ----
__global__ __launch_bounds__(256)
void rescale_attn(float* __restrict__ attn, const float* __restrict__ rinv) {
  const int tid = threadIdx.x;
  const int h   = blockIdx.y;
  const int r0  = blockIdx.x * 8;
  #pragma unroll
  for (int r8 = 0; r8 < 8; ++r8) {
    const float sc = rinv[(size_t)h * S + r0 + r8];           // wave-uniform -> s_load
    f32x4* p = (f32x4*)(attn + ((size_t)h * S + r0 + r8) * S); // 1024 f32x4 per row
    #pragma unroll
    for (int u = 0; u < 4; ++u) {
      const int j = tid + u * 256;
      f32x4 x = __builtin_nontemporal_load(p + j);
      x *= sc;
      __builtin_nontemporal_store(x, p + j);
    }
  }
}

// ===================== single-pass fused kernel =====================
// Block: 256 threads (4 waves). Tile: 64 q-rows x 64 k-cols. Wave w owns q-rows [16w,16w+16).
// Grid: 1024 blocks, XCD-swizzled (each XCD's 128 blocks = 2 heads -> K+V L2-resident).
// Per kt: barrier A -> LDS writes (K, V^T from prefetch regs) -> issue kt+1 loads + mask words
//         -> barrier B -> QK^T -> epilogue stores UNNORMALIZED exp(s) (NT), lsum +=,
//         Ps round-trip -> PV accumulates unnormalized O.
// Epilogue: rinv = 1/lsum; O *= rinv; rinv -> ws for the rescale kernel.
__global__ __launch_bounds__(256, 4)
void sdpa_onepass(const float* __restrict__ q, const float* __restrict__ k,
                  const float* __restrict__ v,
                  const unsigned long long* __restrict__ mbits,
                  float* __restrict__ out, float* __restrict__ attn,
                  float* __restrict__ rinv_out)
{
  // pitch 72 halves = 144 B: rows 16B-aligned for b128 frag reads; 2-way bank alias only (free)
  __shared__ _Float16 Qs[64][72];
  __shared__ _Float16 Ks[64][72];
  __shared__ _Float16 Vts[64][72];    // transposed: Vts[d][n]
  __shared__ _Float16 Ps[4][16][72];  // per-wave P tile (C-layout -> A-layout round trip)

  const int tid  = threadIdx.x;
  const int wave = tid >> 6;
  const int lane = tid & 63;
  const int quad = lane >> 4;
  const int l16  = lane & 15;

  // T1: XCD swizzle (bijective, 1024 % 8 == 0): XCD x hosts heads {2x, 2x+1}.
  const int bid = (int)blockIdx.x;
  const int swz = (bid & 7) * 128 + (bid >> 3);
  const int h   = swz >> 6;
  const int q0  = (swz & 63) * 64;

  const float* __restrict__ qh = q + (size_t)h * S * D;
  const float* __restrict__ kh = k + (size_t)h * S * D;
  const float* __restrict__ vh = v + (size_t)h * S * D;

  // ---- stage Q tile fp32 -> fp16 ----
  #pragma unroll
  for (int t = 0; t < 4; ++t) {
    const int i   = tid + t * 256;   // float4 index 0..1023
    const int row = i >> 4;
    const int c4  = i & 15;
    const float4 f = *(const float4*)(qh + (size_t)(q0 + row) * D + c4 * 4);
    cvt_store(&Qs[row][c4 * 4], f);
  }
  __syncthreads();

  const f16x8 qa0 = *(const f16x8*)&Qs[wave * 16 + l16][quad * 8];
  const f16x8 qa1 = *(const f16x8*)&Qs[wave * 16 + l16][32 + quad * 8];

  const int mrow0 = q0 + wave * 16 + quad * 4;  // global q-row base for this lane (+r, r=0..3)

  // ---- prologue: K0, V0 into regs ----
  float4 kf[4], vf[4];
  #pragma unroll
  for (int t = 0; t < 4; ++t) {
    const int i = tid + t * 256;
    kf[t] = *(const float4*)(kh + (size_t)(i >> 4) * D + (i & 15) * 4);
    vf[t] = *(const float4*)(vh + (size_t)(i & 63) * D + (i >> 6) * 4);
  }

  float lsum[4] = {0.f, 0.f, 0.f, 0.f};
  f32x4 Of[4];
  #pragma unroll
  for (int dt = 0; dt < 4; ++dt) Of[dt] = (f32x4){0.f, 0.f, 0.f, 0.f};

  float* __restrict__ attn_h = attn + (size_t)h * S * S;

  for (int kt = 0; kt < 64; ++kt) {
    __syncthreads();  // A: all waves done reading Ks/Vts of kt-1 (kt=0: no-op vs Qs)

    // LDS writes from prefetch regs (WAR on kf/vf resolved by issue order)
    #pragma unroll
    for (int t = 0; t < 4; ++t) {
      const int i = tid + t * 256;
      cvt_store(&Ks[i >> 4][(i & 15) * 4], kf[t]);
      const int n = i & 63;
      const int c = i >> 6;
      Vts[c * 4 + 0][n] = (_Float16)vf[t].x;
      Vts[c * 4 + 1][n] = (_Float16)vf[t].y;
      Vts[c * 4 + 2][n] = (_Float16)vf[t].z;
      Vts[c * 4 + 3][n] = (_Float16)vf[t].w;
    }
    // issue kt+1 loads now; latency hides under the whole compute phase below
    if (kt < 63) {
      const float* __restrict__ ksrc = kh + (size_t)(kt + 1) * 64 * D;
      const float* __restrict__ vsrc = vh + (size_t)(kt + 1) * 64 * D;
      #pragma unroll
      for (int t = 0; t < 4; ++t) {
        const int i = tid + t * 256;
        kf[t] = *(const float4*)(ksrc + (size_t)(i >> 4) * D + (i & 15) * 4);
        vf[t] = *(const float4*)(vsrc + (size_t)(i & 63) * D + (i >> 6) * 4);
      }
    }
    // mask words issued early; L2-resident (2 MB), hidden by barrier + frag reads
    unsigned long long mw[4];
    #pragma unroll
    for (int r = 0; r < 4; ++r) mw[r] = mbits[(size_t)(mrow0 + r) * SW + kt];

    __syncthreads();  // B: Ks/Vts ready

    const int kk0 = kt * 64;
    #pragma unroll
    for (int nt = 0; nt < 4; ++nt) {
      const f16x8 kb0 = *(const f16x8*)&Ks[nt * 16 + l16][quad * 8];
      const f16x8 kb1 = *(const f16x8*)&Ks[nt * 16 + l16][32 + quad * 8];
      f32x4 acc = {0.f, 0.f, 0.f, 0.f};
      acc = mfma16(qa0, kb0, acc);
      acc = mfma16(qa1, kb1, acc);
      const int col = kk0 + nt * 16 + l16;
      #pragma unroll
      for (int r = 0; r < 4; ++r) {
        const bool masked = ((unsigned)(mw[r] >> (nt * 16)) >> l16) & 1u;
        const float p = masked ? 0.0f : exp2f(acc[r] * kScaleLog2e);  // UNNORMALIZED
        __builtin_nontemporal_store(p, &attn_h[(size_t)(mrow0 + r) * S + col]);
        lsum[r] += p;
        Ps[wave][quad * 4 + r][nt * 16 + l16] = (_Float16)p;
      }
    }

    // P (C-layout) routed through LDS; re-read in A-layout. Same-wave dep: lgkmcnt only.
    const f16x8 pa0 = *(const f16x8*)&Ps[wave][l16][quad * 8];
    const f16x8 pa1 = *(const f16x8*)&Ps[wave][l16][32 + quad * 8];
    __builtin_amdgcn_s_setprio(1);   // T5: phase-diverse blocks share SIMD
    #pragma unroll
    for (int dt = 0; dt < 4; ++dt) {
      const f16x8 vb0 = *(const f16x8*)&Vts[dt * 16 + l16][quad * 8];
      const f16x8 vb1 = *(const f16x8*)&Vts[dt * 16 + l16][32 + quad * 8];
      Of[dt] = mfma16(pa0, vb0, Of[dt]);
      Of[dt] = mfma16(pa1, vb1, Of[dt]);
    }
    __builtin_amdgcn_s_setprio(0);
  }

  // reduce each row's partial sum across its 16 column-lanes (xor 1,2,4,8 stays in quad)
  float rinv[4];
  #pragma unroll
  for (int r = 0; r < 4; ++r) {
    float s = lsum[r];
    s += __shfl_xor(s, 1);
    s += __shfl_xor(s, 2);
    s += __shfl_xor(s, 4);
    s += __shfl_xor(s, 8);
    rinv[r] = 1.0f / s;
  }
  if (l16 == 0) {
    #pragma unroll
    for (int r = 0; r < 4; ++r) rinv_out[(size_t)h * S + mrow0 + r] = rinv[r];
  }

  #pragma unroll
  for (int dt = 0; dt < 4; ++dt)
    #pragma unroll
    for (int r = 0; r < 4; ++r)
      __builtin_nontemporal_store(Of[dt][r] * rinv[r],
          &out[((size_t)h * S + (mrow0 + r)) * D + dt * 16 + l16]);
}

// ===================== fallback (no workspace): R2 two-pass, scalar mask =====================
__global__ __launch_bounds__(256, 4)
void sdpa_twopass(const float* __restrict__ q, const float* __restrict__ k,
                  const float* __restrict__ v, const int* __restrict__ mask,
                  float* __restrict__ out, float* __restrict__ attn)
{
  __shared__ _Float16 Qs[64][72];
  __shared__ _Float16 KV[2][64][72];
  __shared__ _Float16 Ps[4][16][72];

  const int tid  = threadIdx.x;
  const int wave = tid >> 6;
  const int lane = tid & 63;
  const int quad = lane >> 4;
  const int l16  = lane & 15;

  const int bid = (int)blockIdx.x;
  const int swz = (bid & 7) * 128 + (bid >> 3);
  const int h   = swz >> 6;
  const int q0  = (swz & 63) * 64;

  const float* __restrict__ qh = q + (size_t)h * S * D;
  const float* __restrict__ kh = k + (size_t)h * S * D;
  const float* __restrict__ vh = v + (size_t)h * S * D;

  #pragma unroll
  for (int t = 0; t < 4; ++t) {
    const int i   = tid + t * 256;
    const float4 f = *(const float4*)(qh + (size_t)(q0 + (i >> 4)) * D + (i & 15) * 4);
    cvt_store(&Qs[i >> 4][(i & 15) * 4], f);
  }
  __syncthreads();

  const f16x8 qa0 = *(const f16x8*)&Qs[wave * 16 + l16][quad * 8];
  const f16x8 qa1 = *(const f16x8*)&Qs[wave * 16 + l16][32 + quad * 8];
  const int mrow0 = q0 + wave * 16 + quad * 4;

  float4 kf[4];
  #pragma unroll
  for (int t = 0; t < 4; ++t) {
    const int i = tid + t * 256;
    kf[t] = *(const float4*)(kh + (size_t)(i >> 4) * D + (i & 15) * 4);
  }
  #pragma unroll
  for (int t = 0; t < 4; ++t) {
    const int i = tid + t * 256;
    cvt_store(&KV[0][i >> 4][(i & 15) * 4], kf[t]);
  }
  __syncthreads();

  float lsum[4] = {0.f, 0.f, 0.f, 0.f};
  for (int kt = 0; kt < 64; ++kt) {
    const int cur = kt & 1;
    if (kt < 63) {
      const float* __restrict__ src = kh + (size_t)(kt + 1) * 64 * D;
      #pragma unroll
      for (int t = 0; t < 4; ++t) {
        const int i = tid + t * 256;
        kf[t] = *(const float4*)(src + (size_t)(i >> 4) * D + (i & 15) * 4);
      }
    }
    #pragma unroll
    for (int nt = 0; nt < 4; ++nt) {
      const f16x8 kb0 = *(const f16x8*)&KV[cur][nt * 16 + l16][quad * 8];
      const f16x8 kb1 = *(const f16x8*)&KV[cur][nt * 16 + l16][32 + quad * 8];
      f32x4 acc = {0.f, 0.f, 0.f, 0.f};
      acc = mfma16(qa0, kb0, acc);
      acc = mfma16(qa1, kb1, acc);
      #pragma unroll
      for (int r = 0; r < 4; ++r) {
        const int mv = mask[(size_t)(mrow0 + r) * S + (kt * 64 + nt * 16 + l16)];
        lsum[r] += mv ? 0.0f : exp2f(acc[r] * kScaleLog2e);
      }
    }
    if (kt < 63) {
      #pragma unroll
      for (int t = 0; t < 4; ++t) {
        const int i = tid + t * 256;
        cvt_store(&KV[cur ^ 1][i >> 4][(i & 15) * 4], kf[t]);
      }
    }
    __syncthreads();
  }

  float rinv[4];
  #pragma unroll
  for (int r = 0; r < 4; ++r) {
    float s = lsum[r];
    s += __shfl_xor(s, 1); s += __shfl_xor(s, 2);
    s += __shfl_xor(s, 4); s += __shfl_xor(s, 8);
    rinv[r] = 1.0f / s;
  }

  f32x4 Of[4];
  #pragma unroll
  for (int dt = 0; dt < 4; ++dt) Of[dt] = (f32x4){0.f, 0.f, 0.f, 0.f};
  float* __restrict__ attn_h = attn + (size_t)h * S * S;

  #pragma unroll
  for (int t = 0; t < 4; ++t) {
    const int i = tid + t * 256;
    kf[t] = *(const float4*)(kh + (size_t)(i >> 4) * D + (i & 15) * 4);
  }

  for (int kt = 0; kt < 64; ++kt) {
    const int kk0 = kt * 64;
    float4 vf[4];
    #pragma unroll
    for (int t = 0; t < 4; ++t) {
      const int i = tid + t * 256;
      vf[t] = *(const float4*)(vh + (size_t)(kk0 + (i & 63)) * D + (i >> 6) * 4);
    }
    __syncthreads();
    #pragma unroll
    for (int t = 0; t < 4; ++t) {
      const int i = tid + t * 256;
      cvt_store(&KV[0][i >> 4][(i & 15) * 4], kf[t]);
      const int n = i & 63;
      const int c = i >> 6;
      KV[1][c * 4 + 0][n] = (_Float16)vf[t].x;
      KV[1][c * 4 + 1][n] = (_Float16)vf[t].y;
      KV[1][c * 4 + 2][n] = (_Float16)vf[t].z;
      KV[1][c * 4 + 3][n] = (_Float16)vf[t].w;
    }
    if (kt < 63) {
      const float* __restrict__ src = kh + (size_t)(kt + 1) * 64 * D;
      #pragma unroll
      for (int t = 0; t < 4; ++t) {
        const int i = tid + t * 256;
        kf[t] = *(const float4*)(src + (size_t)(i >> 4) * D + (i & 15) * 4);
      }
    }
    __syncthreads();

    #pragma unroll
    for (int nt = 0; nt < 4; ++nt) {
      const f16x8 kb0 = *(const f16x8*)&KV[0][nt * 16 + l16][quad * 8];
      const f16x8 kb1 = *(const f16x8*)&KV[0][nt * 16 + l16][32 + quad * 8];
      f32x4 acc = {0.f, 0.f, 0.f, 0.f};
      acc = mfma16(qa0, kb0, acc);
      acc = mfma16(qa1, kb1, acc);
      const int col = kk0 + nt * 16 + l16;
      #pragma unroll
      for (int r = 0; r < 4; ++r) {
        const int mv = mask[(size_t)(mrow0 + r) * S + col];
        const float p = mv ? 0.0f : exp2f(acc[r] * kScaleLog2e) * rinv[r];
        __builtin_nontemporal_store(p, &attn_h[(size_t)(mrow0 + r) * S + col]);
        Ps[wave][quad * 4 + r][nt * 16 + l16] = (_Float16)p;
      }
    }
    const f16x8 pa0 = *(const f16x8*)&Ps[wave][l16][quad * 8];
    const f16x8 pa1 = *(const f16x8*)&Ps[wave][l16][32 + quad * 8];
    #pragma unroll
    for (int dt = 0; dt < 4; ++dt) {
      const f16x8 vb0 = *(const f16x8*)&KV[1][dt * 16 + l16][quad * 8];
      const f16x8 vb1 = *(const f16x8*)&KV[1][dt * 16 + l16][32 + quad * 8];
      Of[dt] = mfma16(pa0, vb0, Of[dt]);
      Of[dt] = mfma16(pa1, vb1, Of[dt]);
    }
  }
  #pragma unroll
  for (int dt = 0; dt < 4; ++dt)
    #pragma unroll
    for (int r = 0; r < 4; ++r)
      __builtin_nontemporal_store(Of[dt][r],
          &out[((size_t)h * S + (mrow0 + r)) * D + dt * 16 + l16]);
}

extern "C" void kernel_launch(void* const* d_in, const int* in_sizes, int n_in,
                              void* d_out, int out_size, void* d_ws, size_t ws_size,
                              hipStream_t stream) {
  const float* q    = (const float*)d_in[0];
  const float* k    = (const float*)d_in[1];
  const float* v    = (const float*)d_in[2];
  const int*   mask = (const int*)d_in[3];   // bool mask uploaded as int32 per harness convention
  float* out  = (float*)d_out;
  float* attn = out + (size_t)NH * S * D;    // tuple (out, attn) concatenated flat

  const size_t bits_bytes = (size_t)S * (size_t)S / 8;        // 2 MB bitmask
  const size_t rinv_bytes = (size_t)NH * (size_t)S * 4;       // 256 KB row scales
  if (d_ws != nullptr && ws_size >= bits_bytes + rinv_bytes) {
    unsigned long long* mbits = (unsigned long long*)d_ws;
    float* rinv = (float*)((char*)d_ws + bits_bytes);
    pack_mask<<<dim3(1024), 256, 0, stream>>>(mask, mbits);
    sdpa_onepass<<<dim3(1024), 256, 0, stream>>>(q, k, v, mbits, out, attn, rinv);
    rescale_attn<<<dim3(S / 8, NH), 256, 0, stream>>>(attn, rinv);
  } else {
    sdpa_twopass<<<dim3(1024), 256, 0, stream>>>(q, k, v, mask, out, attn);
  }
}

// Round 8
// 1478.397 us; speedup vs baseline: 1.2991x; 1.2991x over previous
//
#include <hip/hip_runtime.h>
#include <hip/hip_fp16.h>

namespace {
constexpr int S  = 4096;
constexpr int D  = 64;
constexpr int NH = 16;
constexpr int SW = S / 64;   // 64 mask words (u64) per row
constexpr float kScaleLog2e = 0.125f * 1.44269504088896340736f; // 1/sqrt(64) * log2(e)

typedef _Float16 f16x8 __attribute__((ext_vector_type(8)));
typedef float    f32x4 __attribute__((ext_vector_type(4)));

__device__ inline f32x4 mfma16(f16x8 a, f16x8 b, f32x4 c) {
  return __builtin_amdgcn_mfma_f32_16x16x32_f16(a, b, c, 0, 0, 0);
}

__device__ inline void cvt_store(_Float16* dst, const float4 f) {
  union { ushort4 u; _Float16 h4[4]; } cv;
  cv.h4[0] = (_Float16)f.x; cv.h4[1] = (_Float16)f.y;
  cv.h4[2] = (_Float16)f.z; cv.h4[3] = (_Float16)f.w;
  *(ushort4*)dst = cv.u;
}
} // namespace

// ---- pack bool-as-int mask (S x S) into u64 bitmask: bit=1 means masked out ----
__global__ void pack_mask(const int* __restrict__ mask, unsigned long long* __restrict__ bits) {
  const int lane = threadIdx.x & 63;
  const int wid  = (int)((blockIdx.x * blockDim.x + threadIdx.x) >> 6);
  const int nwv  = (int)((gridDim.x * blockDim.x) >> 6);
  for (int w = wid; w < S * S / 64; w += nwv) {
    const int mv = mask[(size_t)w * 64 + lane];
    const unsigned long long b = __ballot(mv != 0);
    if (lane == 0) bits[w] = b;
  }
}

// Block: 256 threads (4 waves). Tile: 64 q-rows x 64 k-cols. Wave w owns q-rows [16w,16w+16).
// Grid: 1024 blocks, XCD-swizzled (each XCD's 128 blocks = 2 heads -> K+V L2-resident).
// LDS: 4-buffer pool (36.9 KB). Pass 1 ping-pongs PAIRS of K tiles across {pool2,pool3}/
//      {pool0,pool1} (Q region + Ps region are dead in pass 1) -> ONE barrier per 2 tiles.
// Pass 2: pool0=Ks, pool1=Vts, pool2=Ps. attn stored post-Ps-read as 4x NT dwordx4/lane
//      (contiguous cols) instead of 16 scattered dwords.
__global__ __launch_bounds__(256, 4)
void sdpa_twopass(const float* __restrict__ q, const float* __restrict__ k,
                  const float* __restrict__ v,
                  const unsigned long long* __restrict__ mbits,
                  float* __restrict__ out, float* __restrict__ attn)
{
  // pitch 72 halves = 144 B: rows 16B-aligned for b128 frag reads; 2-way bank alias only (free)
  __shared__ _Float16 pool[4][64][72];

  const int tid  = threadIdx.x;
  const int wave = tid >> 6;
  const int lane = tid & 63;
  const int quad = lane >> 4;
  const int l16  = lane & 15;

  // T1: XCD swizzle (bijective, 1024 % 8 == 0): XCD x hosts heads {2x, 2x+1}.
  const int bid = (int)blockIdx.x;
  const int swz = (bid & 7) * 128 + (bid >> 3);
  const int h   = swz >> 6;
  const int q0  = (swz & 63) * 64;

  const float* __restrict__ qh = q + (size_t)h * S * D;
  const float* __restrict__ kh = k + (size_t)h * S * D;
  const float* __restrict__ vh = v + (size_t)h * S * D;

  // ---- issue K tiles 0,1 early; stage Q tile fp32 -> fp16 into pool[0] ----
  float4 kfa[4], kfb[4];
  #pragma unroll
  for (int t = 0; t < 4; ++t) {
    const int i = tid + t * 256;
    kfa[t] = *(const float4*)(kh + (size_t)(i >> 4) * D + (i & 15) * 4);
    kfb[t] = *(const float4*)(kh + (size_t)(64 + (i >> 4)) * D + (i & 15) * 4);
  }
  #pragma unroll
  for (int t = 0; t < 4; ++t) {
    const int i   = tid + t * 256;   // float4 index 0..1023
    const float4 f = *(const float4*)(qh + (size_t)(q0 + (i >> 4)) * D + (i & 15) * 4);
    cvt_store(&pool[0][i >> 4][(i & 15) * 4], f);
  }
  __syncthreads();

  const f16x8 qa0 = *(const f16x8*)&pool[0][wave * 16 + l16][quad * 8];
  const f16x8 qa1 = *(const f16x8*)&pool[0][wave * 16 + l16][32 + quad * 8];

  const int mrow0 = q0 + wave * 16 + quad * 4;  // global q-row base for this lane (+r, r=0..3)

  // K pair 0 -> pool[2], pool[3] (doesn't touch pool[0]; qa reads drained at next barrier)
  #pragma unroll
  for (int t = 0; t < 4; ++t) {
    const int i = tid + t * 256;
    cvt_store(&pool[2][i >> 4][(i & 15) * 4], kfa[t]);
    cvt_store(&pool[3][i >> 4][(i & 15) * 4], kfb[t]);
  }
  __syncthreads();   // pair 0 ready; all waves' qa reads complete (lgkm drained pre-barrier)

  float lsum[4] = {0.f, 0.f, 0.f, 0.f};

  // ================= pass 1: row sums of exp(scores), 2 tiles per barrier =================
  for (int it = 0; it < 32; ++it) {
    const int A = (it & 1) ? 0 : 2;        // current pair buffers: A, A+1
    if (it < 31) {
      const float* __restrict__ src = kh + (size_t)(2 * it + 2) * 64 * D;
      #pragma unroll
      for (int t = 0; t < 4; ++t) {
        const int i = tid + t * 256;
        kfa[t] = *(const float4*)(src + (size_t)(i >> 4) * D + (i & 15) * 4);
        kfb[t] = *(const float4*)(src + (size_t)(64 + (i >> 4)) * D + (i & 15) * 4);
      }
    }
    unsigned long long mwa[4], mwb[4];
    #pragma unroll
    for (int r = 0; r < 4; ++r) {
      mwa[r] = mbits[(size_t)(mrow0 + r) * SW + 2 * it];
      mwb[r] = mbits[(size_t)(mrow0 + r) * SW + 2 * it + 1];
    }

    #pragma unroll
    for (int half = 0; half < 2; ++half) {
      const _Float16 (*buf)[72] = pool[A + half];
      #pragma unroll
      for (int nt = 0; nt < 4; ++nt) {
        const f16x8 kb0 = *(const f16x8*)&buf[nt * 16 + l16][quad * 8];
        const f16x8 kb1 = *(const f16x8*)&buf[nt * 16 + l16][32 + quad * 8];
        f32x4 acc = {0.f, 0.f, 0.f, 0.f};
        acc = mfma16(qa0, kb0, acc);
        acc = mfma16(qa1, kb1, acc);
        #pragma unroll
        for (int r = 0; r < 4; ++r) {
          const unsigned long long w64 = half ? mwb[r] : mwa[r];
          const bool m = ((unsigned)(w64 >> (nt * 16)) >> l16) & 1u;
          lsum[r] += m ? 0.0f : exp2f(acc[r] * kScaleLog2e);
        }
      }
    }

    if (it < 31) {
      const int W = A ^ 2;   // write the pair NOT being read this iteration
      #pragma unroll
      for (int t = 0; t < 4; ++t) {
        const int i = tid + t * 256;
        cvt_store(&pool[W][i >> 4][(i & 15) * 4], kfa[t]);
        cvt_store(&pool[W + 1][i >> 4][(i & 15) * 4], kfb[t]);
      }
    }
    __syncthreads();   // next pair visible; current pair reads drained
  }

  // reduce each row's partial sum across its 16 column-lanes (xor 1,2,4,8 stays in quad)
  float rinv[4];
  #pragma unroll
  for (int r = 0; r < 4; ++r) {
    float s = lsum[r];
    s += __shfl_xor(s, 1);
    s += __shfl_xor(s, 2);
    s += __shfl_xor(s, 4);
    s += __shfl_xor(s, 8);
    rinv[r] = 1.0f / s;
  }

  // ================= pass 2: write attn, accumulate O = P @ V =================
  f32x4 Of[4];
  #pragma unroll
  for (int dt = 0; dt < 4; ++dt) Of[dt] = (f32x4){0.f, 0.f, 0.f, 0.f};

  float* __restrict__ attn_h = attn + (size_t)h * S * S;
  _Float16 (* __restrict__ Ps)[72] = &pool[2][wave * 16];   // per-wave 16x72 region
  const int arow = q0 + wave * 16 + l16;                    // attn store row for this lane

  // prefetch K tile 0 into regs (latency hidden under pass-1 epilogue)
  #pragma unroll
  for (int t = 0; t < 4; ++t) {
    const int i = tid + t * 256;
    kfa[t] = *(const float4*)(kh + (size_t)(i >> 4) * D + (i & 15) * 4);
  }

  for (int kt = 0; kt < 64; ++kt) {
    const int kk0 = kt * 64;
    // V loads for this tile: issue before the barrier so latency overlaps barrier + K writes
    float4 vf[4];
    #pragma unroll
    for (int t = 0; t < 4; ++t) {
      const int i = tid + t * 256;
      vf[t] = *(const float4*)(vh + (size_t)(kk0 + (i & 63)) * D + (i >> 6) * 4);
    }
    // mask words issued early too: latency hides under barrier + LDS writes below
    unsigned long long mw[4];
    #pragma unroll
    for (int r = 0; r < 4; ++r) mw[r] = mbits[(size_t)(mrow0 + r) * SW + kt];
    __syncthreads();  // prior compute done reading Ks/Vts (kt=0: pass-1 buffers retired)

    #pragma unroll
    for (int t = 0; t < 4; ++t) {
      const int i = tid + t * 256;
      cvt_store(&pool[0][i >> 4][(i & 15) * 4], kfa[t]);   // Ks
      const int n = i & 63;
      const int c = i >> 6;
      pool[1][c * 4 + 0][n] = (_Float16)vf[t].x;           // Vts[d][n]
      pool[1][c * 4 + 1][n] = (_Float16)vf[t].y;
      pool[1][c * 4 + 2][n] = (_Float16)vf[t].z;
      pool[1][c * 4 + 3][n] = (_Float16)vf[t].w;
    }
    // prefetch next K tile into regs; latency hides under this kt's compute phase
    if (kt < 63) {
      const float* __restrict__ src = kh + (size_t)(kt + 1) * 64 * D;
      #pragma unroll
      for (int t = 0; t < 4; ++t) {
        const int i = tid + t * 256;
        kfa[t] = *(const float4*)(src + (size_t)(i >> 4) * D + (i & 15) * 4);
      }
    }
    __syncthreads();

    #pragma unroll
    for (int nt = 0; nt < 4; ++nt) {
      const f16x8 kb0 = *(const f16x8*)&pool[0][nt * 16 + l16][quad * 8];
      const f16x8 kb1 = *(const f16x8*)&pool[0][nt * 16 + l16][32 + quad * 8];
      f32x4 acc = {0.f, 0.f, 0.f, 0.f};
      acc = mfma16(qa0, kb0, acc);
      acc = mfma16(qa1, kb1, acc);
      #pragma unroll
      for (int r = 0; r < 4; ++r) {
        const bool m = ((unsigned)(mw[r] >> (nt * 16)) >> l16) & 1u;
        const float p = m ? 0.0f : exp2f(acc[r] * kScaleLog2e) * rinv[r];
        Ps[quad * 4 + r][nt * 16 + l16] = (_Float16)p;     // C-layout -> A-layout round trip
      }
    }

    // Re-read P in A-layout (same-wave dep: lgkmcnt only), then store attn from pa:
    // lane holds row arow, cols {quad*8..+7} u {32+quad*8..+7} -> 4 contiguous NT dwordx4.
    // NOTE: NT-store address must be an ext_vector pointer (f32x4*), not HIP float4*.
    const f16x8 pa0 = *(const f16x8*)&Ps[l16][quad * 8];
    const f16x8 pa1 = *(const f16x8*)&Ps[l16][32 + quad * 8];
    {
      float* __restrict__ ab = attn_h + (size_t)arow * S + kk0 + quad * 8;
      const f32x4 s0 = {(float)pa0[0], (float)pa0[1], (float)pa0[2], (float)pa0[3]};
      const f32x4 s1 = {(float)pa0[4], (float)pa0[5], (float)pa0[6], (float)pa0[7]};
      const f32x4 s2 = {(float)pa1[0], (float)pa1[1], (float)pa1[2], (float)pa1[3]};
      const f32x4 s3 = {(float)pa1[4], (float)pa1[5], (float)pa1[6], (float)pa1[7]};
      __builtin_nontemporal_store(s0, (f32x4*)ab);
      __builtin_nontemporal_store(s1, (f32x4*)(ab + 4));
      __builtin_nontemporal_store(s2, (f32x4*)(ab + 32));
      __builtin_nontemporal_store(s3, (f32x4*)(ab + 36));
    }

    // T5: phase-diverse blocks share each SIMD; prioritize the pure-MFMA PV cluster.
    __builtin_amdgcn_s_setprio(1);
    #pragma unroll
    for (int dt = 0; dt < 4; ++dt) {
      const f16x8 vb0 = *(const f16x8*)&pool[1][dt * 16 + l16][quad * 8];
      const f16x8 vb1 = *(const f16x8*)&pool[1][dt * 16 + l16][32 + quad * 8];
      Of[dt] = mfma16(pa0, vb0, Of[dt]);
      Of[dt] = mfma16(pa1, vb1, Of[dt]);
    }
    __builtin_amdgcn_s_setprio(0);
  }

  #pragma unroll
  for (int dt = 0; dt < 4; ++dt)
    #pragma unroll
    for (int r = 0; r < 4; ++r)
      __builtin_nontemporal_store(Of[dt][r],
          &out[((size_t)h * S + (mrow0 + r)) * D + dt * 16 + l16]);
}

// ===================== fallback (no workspace): scalar-mask two-pass =====================
__global__ __launch_bounds__(256, 4)
void sdpa_fallback(const float* __restrict__ q, const float* __restrict__ k,
                   const float* __restrict__ v, const int* __restrict__ mask,
                   float* __restrict__ out, float* __restrict__ attn)
{
  __shared__ _Float16 Qs[64][72];
  __shared__ _Float16 KV[2][64][72];
  __shared__ _Float16 Ps[4][16][72];

  const int tid  = threadIdx.x;
  const int wave = tid >> 6;
  const int lane = tid & 63;
  const int quad = lane >> 4;
  const int l16  = lane & 15;

  const int bid = (int)blockIdx.x;
  const int swz = (bid & 7) * 128 + (bid >> 3);
  const int h   = swz >> 6;
  const int q0  = (swz & 63) * 64;

  const float* __restrict__ qh = q + (size_t)h * S * D;
  const float* __restrict__ kh = k + (size_t)h * S * D;
  const float* __restrict__ vh = v + (size_t)h * S * D;

  #pragma unroll
  for (int t = 0; t < 4; ++t) {
    const int i   = tid + t * 256;
    const float4 f = *(const float4*)(qh + (size_t)(q0 + (i >> 4)) * D + (i & 15) * 4);
    cvt_store(&Qs[i >> 4][(i & 15) * 4], f);
  }
  __syncthreads();

  const f16x8 qa0 = *(const f16x8*)&Qs[wave * 16 + l16][quad * 8];
  const f16x8 qa1 = *(const f16x8*)&Qs[wave * 16 + l16][32 + quad * 8];
  const int mrow0 = q0 + wave * 16 + quad * 4;

  float4 kf[4];
  #pragma unroll
  for (int t = 0; t < 4; ++t) {
    const int i = tid + t * 256;
    kf[t] = *(const float4*)(kh + (size_t)(i >> 4) * D + (i & 15) * 4);
  }
  #pragma unroll
  for (int t = 0; t < 4; ++t) {
    const int i = tid + t * 256;
    cvt_store(&KV[0][i >> 4][(i & 15) * 4], kf[t]);
  }
  __syncthreads();

  float lsum[4] = {0.f, 0.f, 0.f, 0.f};
  for (int kt = 0; kt < 64; ++kt) {
    const int cur = kt & 1;
    if (kt < 63) {
      const float* __restrict__ src = kh + (size_t)(kt + 1) * 64 * D;
      #pragma unroll
      for (int t = 0; t < 4; ++t) {
        const int i = tid + t * 256;
        kf[t] = *(const float4*)(src + (size_t)(i >> 4) * D + (i & 15) * 4);
      }
    }
    #pragma unroll
    for (int nt = 0; nt < 4; ++nt) {
      const f16x8 kb0 = *(const f16x8*)&KV[cur][nt * 16 + l16][quad * 8];
      const f16x8 kb1 = *(const f16x8*)&KV[cur][nt * 16 + l16][32 + quad * 8];
      f32x4 acc = {0.f, 0.f, 0.f, 0.f};
      acc = mfma16(qa0, kb0, acc);
      acc = mfma16(qa1, kb1, acc);
      #pragma unroll
      for (int r = 0; r < 4; ++r) {
        const int mv = mask[(size_t)(mrow0 + r) * S + (kt * 64 + nt * 16 + l16)];
        lsum[r] += mv ? 0.0f : exp2f(acc[r] * kScaleLog2e);
      }
    }
    if (kt < 63) {
      #pragma unroll
      for (int t = 0; t < 4; ++t) {
        const int i = tid + t * 256;
        cvt_store(&KV[cur ^ 1][i >> 4][(i & 15) * 4], kf[t]);
      }
    }
    __syncthreads();
  }

  float rinv[4];
  #pragma unroll
  for (int r = 0; r < 4; ++r) {
    float s = lsum[r];
    s += __shfl_xor(s, 1); s += __shfl_xor(s, 2);
    s += __shfl_xor(s, 4); s += __shfl_xor(s, 8);
    rinv[r] = 1.0f / s;
  }

  f32x4 Of[4];
  #pragma unroll
  for (int dt = 0; dt < 4; ++dt) Of[dt] = (f32x4){0.f, 0.f, 0.f, 0.f};
  float* __restrict__ attn_h = attn + (size_t)h * S * S;

  #pragma unroll
  for (int t = 0; t < 4; ++t) {
    const int i = tid + t * 256;
    kf[t] = *(const float4*)(kh + (size_t)(i >> 4) * D + (i & 15) * 4);
  }

  for (int kt = 0; kt < 64; ++kt) {
    const int kk0 = kt * 64;
    float4 vf[4];
    #pragma unroll
    for (int t = 0; t < 4; ++t) {
      const int i = tid + t * 256;
      vf[t] = *(const float4*)(vh + (size_t)(kk0 + (i & 63)) * D + (i >> 6) * 4);
    }
    __syncthreads();
    #pragma unroll
    for (int t = 0; t < 4; ++t) {
      const int i = tid + t * 256;
      cvt_store(&KV[0][i >> 4][(i & 15) * 4], kf[t]);
      const int n = i & 63;
      const int c = i >> 6;
      KV[1][c * 4 + 0][n] = (_Float16)vf[t].x;
      KV[1][c * 4 + 1][n] = (_Float16)vf[t].y;
      KV[1][c * 4 + 2][n] = (_Float16)vf[t].z;
      KV[1][c * 4 + 3][n] = (_Float16)vf[t].w;
    }
    if (kt < 63) {
      const float* __restrict__ src = kh + (size_t)(kt + 1) * 64 * D;
      #pragma unroll
      for (int t = 0; t < 4; ++t) {
        const int i = tid + t * 256;
        kf[t] = *(const float4*)(src + (size_t)(i >> 4) * D + (i & 15) * 4);
      }
    }
    __syncthreads();

    #pragma unroll
    for (int nt = 0; nt < 4; ++nt) {
      const f16x8 kb0 = *(const f16x8*)&KV[0][nt * 16 + l16][quad * 8];
      const f16x8 kb1 = *(const f16x8*)&KV[0][nt * 16 + l16][32 + quad * 8];
      f32x4 acc = {0.f, 0.f, 0.f, 0.f};
      acc = mfma16(qa0, kb0, acc);
      acc = mfma16(qa1, kb1, acc);
      const int col = kk0 + nt * 16 + l16;
      #pragma unroll
      for (int r = 0; r < 4; ++r) {
        const int mv = mask[(size_t)(mrow0 + r) * S + col];
        const float p = mv ? 0.0f : exp2f(acc[r] * kScaleLog2e) * rinv[r];
        __builtin_nontemporal_store(p, &attn_h[(size_t)(mrow0 + r) * S + col]);
        Ps[wave][quad * 4 + r][nt * 16 + l16] = (_Float16)p;
      }
    }
    const f16x8 pa0 = *(const f16x8*)&Ps[wave][l16][quad * 8];
    const f16x8 pa1 = *(const f16x8*)&Ps[wave][l16][32 + quad * 8];
    #pragma unroll
    for (int dt = 0; dt < 4; ++dt) {
      const f16x8 vb0 = *(const f16x8*)&KV[1][dt * 16 + l16][quad * 8];
      const f16x8 vb1 = *(const f16x8*)&KV[1][dt * 16 + l16][32 + quad * 8];
      Of[dt] = mfma16(pa0, vb0, Of[dt]);
      Of[dt] = mfma16(pa1, vb1, Of[dt]);
    }
  }
  #pragma unroll
  for (int dt = 0; dt < 4; ++dt)
    #pragma unroll
    for (int r = 0; r < 4; ++r)
      __builtin_nontemporal_store(Of[dt][r],
          &out[((size_t)h * S + (mrow0 + r)) * D + dt * 16 + l16]);
}

extern "C" void kernel_launch(void* const* d_in, const int* in_sizes, int n_in,
                              void* d_out, int out_size, void* d_ws, size_t ws_size,
                              hipStream_t stream) {
  const float* q    = (const float*)d_in[0];
  const float* k    = (const float*)d_in[1];
  const float* v    = (const float*)d_in[2];
  const int*   mask = (const int*)d_in[3];   // bool mask uploaded as int32 per harness convention
  float* out  = (float*)d_out;
  float* attn = out + (size_t)NH * S * D;    // tuple (out, attn) concatenated flat

  const size_t bits_bytes = (size_t)S * (size_t)S / 8;  // 2 MB bitmask
  if (d_ws != nullptr && ws_size >= bits_bytes) {
    unsigned long long* mbits = (unsigned long long*)d_ws;
    pack_mask<<<dim3(1024), 256, 0, stream>>>(mask, mbits);
    sdpa_twopass<<<dim3(1024), 256, 0, stream>>>(q, k, v, mbits, out, attn);
  } else {
    sdpa_fallback<<<dim3(1024), 256, 0, stream>>>(q, k, v, mask, out, attn);
  }
}